// Round 13
// baseline (59.464 us; speedup 1.0000x reference)
//
#include <hip/hip_runtime.h>
#include <math.h>

#define KEXP 7
#define DDIM 1024
#define RDIM 128
#define TSEQ 2048
#define BBATCH 4
#define TAU_C 1.2f
#define EPS_C 1e-9f
#define LN_EPS_C 1e-5f

// ---- ws int region (4 separate 128-B cache lines), zeroed each call ----
#define CTR0 0      // basis+weights done count (target 36)
#define FLG0 32     // flag: prep done
#define CTR1 64     // sv done count (target 112)
#define FLG1 96     // flag: sv done
// ---- float data from float-offset 128 (byte 512) ----
#define WS_S     128                  // s[b][k][1024]      : 28672 floats
#define WS_BASIS (WS_S + 28672)       // basis[b][128]      : 512
#define WS_W     (WS_BASIS + 512)     // w[b][8]            : 32
#define WS_PSTAT (WS_W + 32)          // pstat[b][k][16][2] : 896

__device__ __forceinline__ float dot4(float4 a, float4 b) {
    return fmaf(a.x, b.x, fmaf(a.y, b.y, fmaf(a.z, b.z, a.w * b.w)));
}

// tid 0 only, after __syncthreads(). One RMW per producer block.
__device__ __forceinline__ void role_done(int* f, int cidx, int fidx, int target) {
    __threadfence();
    int old = __hip_atomic_fetch_add(&f[cidx], 1, __ATOMIC_ACQ_REL, __HIP_MEMORY_SCOPE_AGENT);
    if (old == target - 1)
        __hip_atomic_store(&f[fidx], 1, __ATOMIC_RELEASE, __HIP_MEMORY_SCOPE_AGENT);
}

// tid 0 polls (acquire + s_sleep), then block barrier.
__device__ __forceinline__ void wait_flag(int* f, int fidx, int tid) {
    if (tid == 0) {
        while (__hip_atomic_load(&f[fidx], __ATOMIC_ACQUIRE, __HIP_MEMORY_SCOPE_AGENT) == 0)
            __builtin_amdgcn_s_sleep(16);
    }
    __syncthreads();
}

// ---------------- roles (R3-proven bodies) ----------------

__device__ __forceinline__ void role_basis(int idx, const float* __restrict__ h,
                                           const float* __restrict__ U_w,
                                           float* __restrict__ ws, int lane, int wv) {
    const int b = idx >> 3;
    const int chunk = idx & 7;
    const float4* h4 = (const float4*)(h + ((size_t)b * TSEQ + (TSEQ - 1)) * DDIM);
    float4 hf[4];
#pragma unroll
    for (int j = 0; j < 4; ++j) hf[j] = h4[j * 64 + lane];
    const int r0 = chunk * 16 + wv * 4;
    float part[4];
#pragma unroll
    for (int rr = 0; rr < 4; ++rr) {
        const float4* u4 = (const float4*)(U_w + (size_t)(r0 + rr) * DDIM);
        float a = 0.f;
#pragma unroll
        for (int j = 0; j < 4; ++j) a += dot4(hf[j], u4[j * 64 + lane]);
        part[rr] = a;
    }
#pragma unroll
    for (int off = 32; off > 0; off >>= 1)
#pragma unroll
        for (int rr = 0; rr < 4; ++rr)
            part[rr] += __shfl_xor(part[rr], off, 64);
    if (lane == 0) {
#pragma unroll
        for (int rr = 0; rr < 4; ++rr)
            ws[WS_BASIS + b * RDIM + r0 + rr] = part[rr];
    }
}

__device__ __forceinline__ void role_weights(int b, const float* __restrict__ h,
                                             const float* __restrict__ gate_w,
                                             const float* __restrict__ gate_b,
                                             float* __restrict__ ws, float* sA,
                                             int tid, int lane, int wv) {
    const float4* h4 = (const float4*)(h + ((size_t)b * TSEQ + (TSEQ - 1)) * DDIM);
    for (int e = wv; e < KEXP; e += 4) {
        const float4* gw4 = (const float4*)(gate_w + (size_t)e * DDIM);
        float a = 0.f;
#pragma unroll
        for (int j = 0; j < 4; ++j) a += dot4(h4[j * 64 + lane], gw4[j * 64 + lane]);
#pragma unroll
        for (int off = 32; off > 0; off >>= 1) a += __shfl_xor(a, off, 64);
        if (lane == 0) sA[e] = a + gate_b[e];
    }
    __syncthreads();
    if (tid == 0) {
        float l0[KEXP], m0 = -1e30f;
#pragma unroll
        for (int j = 0; j < KEXP; ++j) { l0[j] = sA[j]; m0 = fmaxf(m0, l0[j]); }
        float es0 = 0.f, g[KEXP];
#pragma unroll
        for (int j = 0; j < KEXP; ++j) { g[j] = expf(l0[j] - m0); es0 += g[j]; }
        const float inv0 = 1.f / es0;
#pragma unroll
        for (int j = 0; j < KEXP; ++j) g[j] *= inv0;
        int i1 = 0;
        for (int j = 1; j < KEXP; ++j) if (g[j] > g[i1]) i1 = j;
        int i2 = -1;
        for (int j = 0; j < KEXP; ++j)
            if (j != i1 && (i2 < 0 || g[j] > g[i2])) i2 = j;
        int i3 = -1;
        for (int j = 0; j < KEXP; ++j)
            if (j != i1 && j != i2 && (i3 < 0 || g[j] > g[i3])) i3 = j;
        int i4 = -1;
        for (int j = 0; j < KEXP; ++j)
            if (j != i1 && j != i2 && j != i3 && (i4 < 0 || g[j] > g[i4])) i4 = j;
        float s = fmaxf(g[i3] + g[i4], EPS_C);
        float p[KEXP];
#pragma unroll
        for (int j = 0; j < KEXP; ++j) p[j] = 0.f;
        p[i3] = g[i3] / s;
        p[i4] = g[i4] / s;
        float l[KEXP], m = -1e30f;
#pragma unroll
        for (int j = 0; j < KEXP; ++j) {
            l[j] = logf(fmaxf(p[j], EPS_C)) * (1.f / TAU_C);
            m = fmaxf(m, l[j]);
        }
        float es = 0.f, w[KEXP];
#pragma unroll
        for (int j = 0; j < KEXP; ++j) { w[j] = expf(l[j] - m); es += w[j]; }
        const float inv = 1.f / es;
        float wsum = 0.f;
#pragma unroll
        for (int j = 0; j < KEXP; ++j) { w[j] *= inv; wsum += w[j]; ws[WS_W + b * 8 + j] = w[j]; }
        ws[WS_W + b * 8 + 7] = wsum;
    }
}

// one 16-row gate chunk. __noinline__ keeps its 28-float4 staging out of other paths.
__device__ __noinline__ void gate_chunk(int c, const float* __restrict__ h,
                                        const float* __restrict__ gate_w,
                                        const float* __restrict__ gate_b,
                                        float* __restrict__ G,
                                        int lane, int wv) {
    const float4* gw4 = (const float4*)gate_w;
    float4 gw[KEXP][4];
#pragma unroll
    for (int k = 0; k < KEXP; ++k)
#pragma unroll
        for (int j = 0; j < 4; ++j)
            gw[k][j] = gw4[k * 256 + j * 64 + lane];
    float gb[KEXP];
#pragma unroll
    for (int k = 0; k < KEXP; ++k) gb[k] = gate_b[k];

    const int row0 = c * 16 + wv * 4;
#pragma unroll
    for (int r = 0; r < 4; ++r) {
        const int row = row0 + r;
        const float4* h4 = (const float4*)(h + (size_t)row * DDIM);
        float acc[KEXP];
#pragma unroll
        for (int k = 0; k < KEXP; ++k) acc[k] = 0.f;
#pragma unroll
        for (int j = 0; j < 4; ++j) {
            float4 hv = h4[j * 64 + lane];
#pragma unroll
            for (int k = 0; k < KEXP; ++k) {
                acc[k] = fmaf(hv.x, gw[k][j].x, acc[k]);
                acc[k] = fmaf(hv.y, gw[k][j].y, acc[k]);
                acc[k] = fmaf(hv.z, gw[k][j].z, acc[k]);
                acc[k] = fmaf(hv.w, gw[k][j].w, acc[k]);
            }
        }
#pragma unroll
        for (int k = 0; k < KEXP; ++k) {
#pragma unroll
            for (int off = 32; off > 0; off >>= 1)
                acc[k] += __shfl_xor(acc[k], off, 64);
        }
        float m = -1e30f;
#pragma unroll
        for (int k = 0; k < KEXP; ++k) { acc[k] += gb[k]; m = fmaxf(m, acc[k]); }
        float e[KEXP];
        float s = 0.f;
#pragma unroll
        for (int k = 0; k < KEXP; ++k) { e[k] = expf(acc[k] - m); s += e[k]; }
        const float inv = 1.f / s;
        if (lane == 0) {
#pragma unroll
            for (int k = 0; k < KEXP; ++k) G[row * KEXP + k] = e[k] * inv;
        }
    }
}

// comp role (R3-proven): stats finalize + bvec in LDS + matvec for 4 e's.
__device__ __forceinline__ void role_comp(int cb_idx, const float* __restrict__ ws,
                                          const float* __restrict__ ln_g,
                                          const float* __restrict__ ln_b,
                                          const float* __restrict__ comp_w,
                                          const float* __restrict__ comp_b,
                                          float* __restrict__ out,
                                          float* sA, float4* sB,
                                          int tid, int lane, int wv) {
    if (tid < BBATCH * KEXP) {
        const int b = tid / KEXP;
        const int k = tid % KEXP;
        float s1 = 0.f, s2 = 0.f;
#pragma unroll
        for (int c = 0; c < 16; ++c) {
            s1 += ws[WS_PSTAT + ((b * KEXP + k) * 16 + c) * 2 + 0];
            s2 += ws[WS_PSTAT + ((b * KEXP + k) * 16 + c) * 2 + 1];
        }
        const float mu = s1 * (1.f / (float)DDIM);
        const float var = s2 * (1.f / (float)DDIM) - mu * mu;
        const float rs = rsqrtf(var + LN_EPS_C);
        const float w = ws[WS_W + b * 8 + k];
        sA[b * KEXP + k] = w * rs;            // alpha
        sA[28 + b * KEXP + k] = w * rs * mu;  // alpha*mu
    }
    __syncthreads();
    if (tid < BBATCH) {
        float c = 0.f;
#pragma unroll
        for (int k = 0; k < KEXP; ++k) c += sA[28 + tid * KEXP + k];
        sA[56 + tid] = c;                      // Cb
        sA[60 + tid] = ws[WS_W + tid * 8 + 7]; // wsum
    }
    __syncthreads();

    {
        const float4 g4 = ((const float4*)ln_g)[tid];
        const float4 b4 = ((const float4*)ln_b)[tid];
        const float4* s4p = (const float4*)(ws + WS_S);
#pragma unroll
        for (int b = 0; b < BBATCH; ++b) {
            float4 s = make_float4(0.f, 0.f, 0.f, 0.f);
#pragma unroll
            for (int k = 0; k < KEXP; ++k) {
                const float a = sA[b * KEXP + k];
                float4 v = s4p[(size_t)(b * KEXP + k) * 256 + tid];
                s.x = fmaf(a, v.x, s.x);
                s.y = fmaf(a, v.y, s.y);
                s.z = fmaf(a, v.z, s.z);
                s.w = fmaf(a, v.w, s.w);
            }
            const float C = sA[56 + b], wsum = sA[60 + b];
            float4 o;
            o.x = g4.x * (s.x - C) + b4.x * wsum;
            o.y = g4.y * (s.y - C) + b4.y * wsum;
            o.z = g4.z * (s.z - C) + b4.z * wsum;
            o.w = g4.w * (s.w - C) + b4.w * wsum;
            sB[b * 256 + tid] = o;
        }
    }
    __syncthreads();

    const int e = cb_idx * 4 + wv;
    const float4* cw4 = (const float4*)(comp_w + (size_t)e * DDIM);
    float acc[BBATCH] = {0.f, 0.f, 0.f, 0.f};
#pragma unroll
    for (int j = 0; j < 4; ++j) {
        float4 c = cw4[j * 64 + lane];
#pragma unroll
        for (int b = 0; b < BBATCH; ++b) acc[b] += dot4(c, sB[b * 256 + j * 64 + lane]);
    }
#pragma unroll
    for (int b = 0; b < BBATCH; ++b)
#pragma unroll
        for (int off = 32; off > 0; off >>= 1)
            acc[b] += __shfl_xor(acc[b], off, 64);
    if (lane == 0) {
        const float cb = comp_b[e];
#pragma unroll
        for (int b = 0; b < BBATCH; ++b)
            out[b * DDIM + e] = acc[b] + cb;
    }
}

// ===================== single fused kernel, 548 blocks =====================
// bid 0..111:   sv (V reg-prefetch at t=0; wait FLG0; sv; CTR1) + gate 436+bid (bid<76)
// bid 112..143: basis(bid-112); CTR0; gate chunk bid-112   (chunks 0..31)
// bid 144..147: weights(bid-144); CTR0; gate chunk bid-112 (chunks 32..35)
// bid 148..403: gate chunk bid-112 (36..291); wait FLG1; comp(bid-148)
// bid 404..547: gate chunk bid-112 (292..435)
// __launch_bounds__(256,3): 3 blocks/CU -> 768 slots >= 548 -> all co-resident.
__global__ __launch_bounds__(256, 3) void k_mega(const float* __restrict__ h,
                                                 const float* __restrict__ gate_w,
                                                 const float* __restrict__ gate_b,
                                                 const float* __restrict__ U_w,
                                                 const float* __restrict__ V,
                                                 const float* __restrict__ ln_g,
                                                 const float* __restrict__ ln_b,
                                                 const float* __restrict__ comp_w,
                                                 const float* __restrict__ comp_b,
                                                 float* __restrict__ G,
                                                 float* __restrict__ out,
                                                 float* __restrict__ ws) {
    int* flags = (int*)ws;
    const int bid = blockIdx.x;
    const int tid = threadIdx.x;
    const int lane = tid & 63;
    const int wv = tid >> 6;

    __shared__ float sA[512];
    __shared__ float4 sB[1024];

    if (bid < 112) {
        // ---------------- sv ----------------
        const int k = bid >> 4;
        const int chunk = bid & 15;
        const int col = tid & 15;
        const int rc = tid >> 4;

        // V prefetch into registers immediately (no dependency) — streams under h
        const float4* V4 = (const float4*)(V + (size_t)k * RDIM * DDIM);
        float4 v[8];
#pragma unroll
        for (int rr = 0; rr < 8; ++rr)
            v[rr] = V4[(size_t)(rc * 8 + rr) * 256 + chunk * 16 + col];

        wait_flag(flags, FLG0, tid);

        sA[tid] = ws[WS_BASIS + tid];
        sA[tid + 256] = ws[WS_BASIS + tid + 256];
        __syncthreads();

        float4 acc[BBATCH];
#pragma unroll
        for (int b = 0; b < BBATCH; ++b) acc[b] = make_float4(0.f, 0.f, 0.f, 0.f);
#pragma unroll
        for (int rr = 0; rr < 8; ++rr) {
            const int r = rc * 8 + rr;
#pragma unroll
            for (int b = 0; b < BBATCH; ++b) {
                const float br = sA[b * RDIM + r];
                acc[b].x = fmaf(br, v[rr].x, acc[b].x);
                acc[b].y = fmaf(br, v[rr].y, acc[b].y);
                acc[b].z = fmaf(br, v[rr].z, acc[b].z);
                acc[b].w = fmaf(br, v[rr].w, acc[b].w);
            }
        }
#pragma unroll
        for (int b = 0; b < BBATCH; ++b) sB[(rc * 4 + b) * 16 + col] = acc[b];
        __syncthreads();

        if (tid < 64) {
            const int b = tid >> 4;
            const int c = tid & 15;
            float4 s4 = make_float4(0.f, 0.f, 0.f, 0.f);
#pragma unroll
            for (int q = 0; q < 16; ++q) {
                float4 p = sB[(q * 4 + b) * 16 + c];
                s4.x += p.x; s4.y += p.y; s4.z += p.z; s4.w += p.w;
            }
            ((float4*)(ws + WS_S))[(size_t)(b * KEXP + k) * 256 + chunk * 16 + c] = s4;
            float p1 = s4.x + s4.y + s4.z + s4.w;
            float p2 = dot4(s4, s4);
#pragma unroll
            for (int off = 8; off > 0; off >>= 1) {
                p1 += __shfl_xor(p1, off, 64);
                p2 += __shfl_xor(p2, off, 64);
            }
            if (c == 0) {
                ws[WS_PSTAT + ((b * KEXP + k) * 16 + chunk) * 2 + 0] = p1;
                ws[WS_PSTAT + ((b * KEXP + k) * 16 + chunk) * 2 + 1] = p2;
            }
        }
        __syncthreads();
        if (tid == 0) role_done(flags, CTR1, FLG1, 112);

        if (bid < 76) gate_chunk(436 + bid, h, gate_w, gate_b, G, lane, wv);
    } else if (bid < 144) {
        role_basis(bid - 112, h, U_w, ws, lane, wv);
        __syncthreads();
        if (tid == 0) role_done(flags, CTR0, FLG0, 36);
        gate_chunk(bid - 112, h, gate_w, gate_b, G, lane, wv);
    } else if (bid < 148) {
        role_weights(bid - 144, h, gate_w, gate_b, ws, sA, tid, lane, wv);
        __syncthreads();
        if (tid == 0) role_done(flags, CTR0, FLG0, 36);
        gate_chunk(bid - 112, h, gate_w, gate_b, G, lane, wv);
    } else if (bid < 404) {
        gate_chunk(bid - 112, h, gate_w, gate_b, G, lane, wv);
        wait_flag(flags, FLG1, tid);
        role_comp(bid - 148, ws, ln_g, ln_b, comp_w, comp_b, out, sA, sB, tid, lane, wv);
    } else {
        gate_chunk(bid - 112, h, gate_w, gate_b, G, lane, wv);
    }
}

extern "C" void kernel_launch(void* const* d_in, const int* in_sizes, int n_in,
                              void* d_out, int out_size, void* d_ws, size_t ws_size,
                              hipStream_t stream) {
    const float* h      = (const float*)d_in[0];
    const float* gate_w = (const float*)d_in[1];
    const float* gate_b = (const float*)d_in[2];
    const float* U_w    = (const float*)d_in[3];
    const float* V      = (const float*)d_in[4];
    const float* ln_g   = (const float*)d_in[5];
    const float* ln_b   = (const float*)d_in[6];
    const float* comp_w = (const float*)d_in[7];
    const float* comp_b = (const float*)d_in[8];

    float* out = (float*)d_out;                 // b: 4*1024 floats
    float* G   = out + BBATCH * DDIM;           // G: 4*2048*7 floats
    float* ws  = (float*)d_ws;

    // zero the 4 counter/flag lines (512 B) every call — deterministic
    hipMemsetAsync(d_ws, 0, 512, stream);
    k_mega<<<548, 256, 0, stream>>>(h, gate_w, gate_b, U_w, V, ln_g, ln_b,
                                    comp_w, comp_b, G, out, ws);
}